// Round 11
// baseline (361.989 us; speedup 1.0000x reference)
//
#include <hip/hip_runtime.h>

// ws layout (floats):
//   [128..202]       quantized w_conv (75)
//   [256..44159]     quantized w_fc1 TRANSPOSED [j=343][o=128]
//   [44160..44671]   quantized w_fc2 [4][128]
//   [45056..749567]  feat [2048][344] (pooled conv outputs, +pad col = 0)
#define WS_WCONV   128
#define WS_W1T     256
#define WS_W2      44160
#define WS_FEAT    45056

__device__ __forceinline__ float q4(float w, float s) {
  if (s <= 0.f) return 0.f;
  float r = rintf(w / s);                     // round-half-even == jnp.round
  r = fminf(fmaxf(r, -8.f), 7.f);
  return r * s;
}

// Single quant dispatch (proven, absmax 0): every fc1 block redundantly
// computes global max|w1| (172 KB, L2/LLC-cheap). Block 88: conv + fc2.
__global__ __launch_bounds__(256) void quant_all(
    const float* __restrict__ wconv, const float* __restrict__ w1,
    const float* __restrict__ w2, float* __restrict__ ws) {
  __shared__ float red[256];
  int b = blockIdx.x, t = threadIdx.x;
  if (b < 88) {
    const float4* w4 = (const float4*)w1;     // 43904/4 == 10976
    float m = 0.f;
    for (int i = t; i < 10976; i += 256) {
      float4 v = w4[i];
      m = fmaxf(m, fmaxf(fmaxf(fabsf(v.x), fabsf(v.y)),
                         fmaxf(fabsf(v.z), fabsf(v.w))));
    }
    red[t] = m;
    __syncthreads();
    for (int s = 128; s > 0; s >>= 1) {
      if (t < s) red[t] = fmaxf(red[t], red[t + s]);
      __syncthreads();
    }
    float s = red[0] * (1.0f / 7.0f);
    #pragma unroll
    for (int k = 0; k < 2; ++k) {
      int idx = b * 512 + k * 256 + t;
      if (idx < 43904) {
        float q = q4(w1[idx], s);
        int o = idx / 343;
        int j = idx - o * 343;
        ws[WS_W1T + j * 128 + o] = q;         // transpose for coalesced FC1
      }
    }
  } else {
    float mc = (t < 75) ? fabsf(wconv[t]) : 0.f;
    float m2 = 0.f;
    for (int i = t; i < 512; i += 256) m2 = fmaxf(m2, fabsf(w2[i]));
    red[t] = mc;
    __syncthreads();
    for (int s = 128; s > 0; s >>= 1) {
      if (t < s) red[t] = fmaxf(red[t], red[t + s]);
      __syncthreads();
    }
    float sc = red[0] * (1.0f / 7.0f);
    __syncthreads();
    red[t] = m2;
    __syncthreads();
    for (int s = 128; s > 0; s >>= 1) {
      if (t < s) red[t] = fmaxf(red[t], red[t + s]);
      __syncthreads();
    }
    float s2 = red[0] * (1.0f / 7.0f);
    if (t < 75) ws[WS_WCONV + t] = q4(wconv[t], sc);
    #pragma unroll
    for (int k = 0; k < 2; ++k) {
      int idx = k * 256 + t;
      ws[WS_W2 + idx] = q4(w2[idx], s2);
    }
  }
}

// 16-byte load with only 4-byte alignment guarantee (global rows stride 31).
struct __align__(4) f4u { float x, y, z, w; };

// TWO ph-outputs (ph0, ph0+1) of ONE output column pw, one depth pd.
// For i=0 this is line-for-line the R9-proven body (same loads, same fma
// order). For i=1 it reads the identical addresses R9's ph0+1 thread read:
// rp = ph0*62 + hg*31 with hg = hh+2  ==  (ph0+1)*62 + hh*31. Rows hg=2,3
// are shared between the two outputs -> 6 rows instead of 8 per depth.
// Per-accumulator fma order: dd asc, hg asc (=> hh asc), kw inner — exactly
// R9 -> bit-identical feat values.
__device__ __forceinline__ void conv_2ph(
    const float* __restrict__ bcol,  // x + batch*15376 + pd*1984 + ph0*62 + pw*4
    const float* __restrict__ wq, bool i1ok, float bc,
    float* __restrict__ fcol) {      // &feat[batch*344 + pd*49 + ph0*7 + pw]
  float c[2][2][2][2];               // [i][odp][ohp][owp]
  #pragma unroll
  for (int k = 0; k < 16; ++k) ((float*)c)[k] = 0.f;
  #pragma unroll
  for (int dd = 0; dd < 7; ++dd) {
    const float* rb = bcol + dd * 496;
    #pragma unroll
    for (int hg = 0; hg < 6; ++hg) {
      if (hg >= 4 && !i1ok) continue;         // rows 4,5 feed only i=1
      const float* rp = rb + hg * 31;
      f4u A = *(const f4u*)rp;                // cols 4pw .. 4pw+3
      f4u B = *(const f4u*)(rp + 3);          // cols 4pw+3 .. 4pw+6
      float row[7] = {A.x, A.y, A.z, A.w, B.y, B.z, B.w};
      #pragma unroll
      for (int i = 0; i < 2; ++i) {
        int hh = hg - 2 * i;
        if (hh < 0 || hh > 3) continue;       // folds at compile time
        #pragma unroll
        for (int odp = 0; odp < 2; ++odp) {
          int kd = dd - 2 * odp;
          if (kd < 0 || kd > 4) continue;     // folds at compile time
          #pragma unroll
          for (int ohp = 0; ohp < 2; ++ohp) {
            int kh = hh - ohp;
            if (kh < 0 || kh > 2) continue;   // folds at compile time
            #pragma unroll
            for (int owp = 0; owp < 2; ++owp) {
              float a = c[i][odp][ohp][owp];
              #pragma unroll
              for (int kw = 0; kw < 5; ++kw)
                a = fmaf(row[2 * owp + kw], wq[kd * 15 + kh * 5 + kw], a);
              c[i][odp][ohp][owp] = a;
            }
          }
        }
      }
    }
  }
  #pragma unroll
  for (int i = 0; i < 2; ++i) {
    if (i == 1 && !i1ok) continue;
    float m = c[i][0][0][0];
    m = fmaxf(m, c[i][0][0][1]);
    m = fmaxf(m, c[i][0][1][0]);
    m = fmaxf(m, c[i][0][1][1]);
    m = fmaxf(m, c[i][1][0][0]);
    m = fmaxf(m, c[i][1][0][1]);
    m = fmaxf(m, c[i][1][1][0]);
    m = fmaxf(m, c[i][1][1][1]);
    fcol[i * 7] = m + bc;                     // ph = ph0 + i
  }
}

// Conv+pool: each thread owns (batch, pd, ph-pair, pw-pair) and runs
// conv_2ph twice (pw0 always; pw0+1 if valid). Two R9-scale passes of 16
// accumulators each — no 32-acc monolith (R10 suspect). Load stream -21%
// vs R9 (6 shared rows per depth for 2 ph-outputs), threads 3x fewer.
__global__ __launch_bounds__(256, 4) void conv_pool(
    const float* __restrict__ x, const float* __restrict__ bconv,
    const float* __restrict__ ws, float* __restrict__ feat_g) {
  int gid = blockIdx.x * 256 + threadIdx.x;   // < 2048*112 = 229376
  // batch = gid/112 (magic: 112*38347923 - 2^32 = 80; exact for gid < 53M)
  int batch = (int)(((unsigned long long)(unsigned)gid * 38347923ull) >> 32);
  int rem = gid - batch * 112;                // 112 = 7*16
  int pd  = rem >> 4;
  int phb = (rem >> 2) & 3;
  int pwb = rem & 3;
  int ph0 = phb * 2, pw0 = pwb * 2;
  bool i1ok = (phb < 3), j1ok = (pwb < 3);    // second row/col of tile valid
  const float* wq = ws + WS_WCONV;
  float bc = bconv[0];
  const float* xb = x + (size_t)batch * 15376 + pd * 1984 + ph0 * 62;
  float* fb = feat_g + (size_t)batch * 344 + pd * 49 + ph0 * 7;

  conv_2ph(xb + pw0 * 4, wq, i1ok, bc, fb + pw0);
  if (j1ok)
    conv_2ph(xb + pw0 * 4 + 4, wq, i1ok, bc, fb + pw0 + 1);
  if (rem == 0) feat_g[(size_t)batch * 344 + 343] = 0.f;  // pad for FC1 quads
}

// FC1+FC2+softmax, 2 batches per block (1024 blocks -> 4 blocks/CU,
// 16 waves/CU). w1T quad loaded once, fma'd into 2 batch accumulators.
// Per-batch fma order byte-identical to the proven kernel -> absmax 0.
__global__ __launch_bounds__(256) void fc_net(
    const float* __restrict__ ws, const float* __restrict__ bfc1,
    const float* __restrict__ bfc2, float* __restrict__ out) {
  __shared__ alignas(16) float feat[2][344];
  __shared__ float fc1p[2][128];
  __shared__ float a1[2][128];
  __shared__ float s2[2][4];
  int t = threadIdx.x;
  int b0 = blockIdx.x * 2;

  // stage 2 batches' feat (172 f4) -> LDS
  {
    const float4* src = (const float4*)(ws + WS_FEAT + (size_t)b0 * 344);
    float4* dst = (float4*)&feat[0][0];
    if (t < 172) dst[t] = src[t];
  }
  __syncthreads();

  // FC1: g = j-half, o = output; 43 quads per half (g=1 tail uses
  // feat[343]=0; w1T row 343 lands in finite W2 region * 0.0 -> exact).
  int g = t >> 7, o = t & 127;
  {
    const float* wp = ws + WS_W1T + (g ? 172 * 128 : 0) + o;
    int j0 = g ? 172 : 0;
    float q0[2], q1[2], q2[2], q3[2];
    #pragma unroll
    for (int bb = 0; bb < 2; ++bb) { q0[bb] = q1[bb] = q2[bb] = q3[bb] = 0.f; }
    for (int k = 0; k < 43; ++k) {
      float w0 = wp[0], w1 = wp[128], w2 = wp[256], w3 = wp[384];
      #pragma unroll
      for (int bb = 0; bb < 2; ++bb) {
        float4 ff = *(const float4*)&feat[bb][j0 + k * 4];
        q0[bb] = fmaf(ff.x, w0, q0[bb]);
        q1[bb] = fmaf(ff.y, w1, q1[bb]);
        q2[bb] = fmaf(ff.z, w2, q2[bb]);
        q3[bb] = fmaf(ff.w, w3, q3[bb]);
      }
      wp += 512;
    }
    #pragma unroll
    for (int bb = 0; bb < 2; ++bb) {
      float acc = (q0[bb] + q1[bb]) + (q2[bb] + q3[bb]);
      if (g) fc1p[bb][o] = acc;
      else   a1[bb][o] = acc;                 // partial; finished below
    }
    __syncthreads();
    #pragma unroll
    for (int bb = 0; bb < 2; ++bb)
      if (!g) a1[bb][o] = fmaxf(a1[bb][o] + fc1p[bb][o] + bfc1[o], 0.f);
  }
  __syncthreads();

  // FC2: waves 0,1 handle batches 0,1; lane l=(kk,cls), shuffle-reduce.
  if (t < 128) {
    int w = t >> 6, l = t & 63;
    int cls = l & 3, kk = l >> 2;             // kk 0..15, 8 k's each
    const float* w2p = ws + WS_W2 + cls * 128 + kk * 8;
    const float* av = &a1[w][kk * 8];
    float p = 0.f;
    #pragma unroll
    for (int i = 0; i < 8; ++i) p = fmaf(av[i], w2p[i], p);
    p += __shfl_down(p, 32);
    p += __shfl_down(p, 16);
    p += __shfl_down(p, 8);
    p += __shfl_down(p, 4);
    if (l < 4) s2[w][l] = p + bfc2[l];
  }
  __syncthreads();
  // softmax + store: thread t<8 -> (batch w, class cls)
  if (t < 8) {
    int w = t >> 2, cls = t & 3;
    float v0 = s2[w][0], v1 = s2[w][1], v2 = s2[w][2], v3 = s2[w][3];
    float m = fmaxf(fmaxf(v0, v1), fmaxf(v2, v3));
    float e0 = expf(v0 - m), e1 = expf(v1 - m);
    float e2 = expf(v2 - m), e3 = expf(v3 - m);
    float inv = 1.f / (e0 + e1 + e2 + e3);
    float mine = (cls == 0) ? e0 : (cls == 1) ? e1 : (cls == 2) ? e2 : e3;
    out[(b0 + w) * 4 + cls] = mine * inv;
  }
}

extern "C" void kernel_launch(void* const* d_in, const int* in_sizes, int n_in,
                              void* d_out, int out_size, void* d_ws, size_t ws_size,
                              hipStream_t stream) {
  const float* x     = (const float*)d_in[0];
  const float* wconv = (const float*)d_in[1];
  const float* bconv = (const float*)d_in[2];
  const float* wfc1  = (const float*)d_in[3];
  const float* bfc1  = (const float*)d_in[4];
  const float* wfc2  = (const float*)d_in[5];
  const float* bfc2  = (const float*)d_in[6];
  float* out = (float*)d_out;
  float* ws  = (float*)d_ws;

  quant_all<<<89, 256, 0, stream>>>(wconv, wfc1, wfc2, ws);
  conv_pool<<<896, 256, 0, stream>>>(x, bconv, ws, ws + WS_FEAT);
  fc_net<<<1024, 256, 0, stream>>>(ws, bfc1, bfc2, out);
}